// Round 13
// baseline (204.598 us; speedup 1.0000x reference)
//
#include <hip/hip_runtime.h>
#include <hip/hip_fp16.h>

// AudioStructuralAnalyzer fused kernel, round 15.
// vs round 14 (106.3 us; op cuts offset by conflicts 13.6M->16.9M):
// Two same-category LDS-op cuts, bit-identical math, same slot structure:
//  - PP-interleave: (trace,diff)+(sxy,tin) packed as uint2/px in s_PP.
//    B writes b64+b32 (was 3x b32); one vpassPP replaces two vpass4;
//    D23 h-pass reads 3x b128 (was 6x b64).
//  - Phase B row-pair x col-pair items (19x19=361, single pass): 8 b64
//    x-reads per 4 px (was 12).
//  - Buffer aliasing keeps LDS at 37248 B -> 4 blocks/CU:
//    scratchA (P2 gaussian-v) and scratchB (u gaussian-v) live in dead
//    s_PP; x^2-f32 gaussian-v lives in dead s_P2.
// Per-output arithmetic chains preserved -> absmax stays 0.00390625.

#define F_DIM 256
#define T_DIM 2048
#define B_DIM 8
#define C_DIM 2
#define TILE  32
#define NTHR  512

#define XROWS 40          // x tile: halo 4
#define XS    40          // 20 float2 / 10 float4 per row
#define UROWS 38          // (ux,uy): halo 3
#define US    40          // +1 col shift; 20 uint2 / 10 uint4 per row
#define FROWS 36          // field tiles: halo 2
#define FS    36          // px per row
#define FH2   18          // uint2 per h2-row
#define FH4   9           // uint4 per h2-row
#define PPW4  18          // uint4 per PP row (36 px x 8B / 16B)
#define EPSF  1e-10f

template<bool V> struct BoolC { static constexpr bool value = V; };

static __device__ __forceinline__ __half2 pack_h2(float a, float b) {
    auto v = __builtin_amdgcn_cvt_pkrtz(a, b);   // v_cvt_pkrtz_f16_f32
    return *(__half2*)&v;
}
static __device__ __forceinline__ float clamp01(float x) {
    return fminf(fmaxf(x, 0.f), 1.f);
}
static __device__ __forceinline__ __half2 u2h(unsigned v) {
    return *(const __half2*)&v;
}

__global__ __launch_bounds__(512, 4)
void audio_struct_fused(const float* __restrict__ x_in,
                        const float* __restrict__ gk_in,
                        float* __restrict__ out)
{
    __shared__ __align__(16) float   s_x  [XROWS*XS];    // 6400 B
    __shared__ __align__(16) __half2 s_u  [UROWS*US];    // 6080 B (ux,uy), col-shifted
    __shared__ __align__(16) uint2   s_PP [FROWS*FS];    // 10368 B {(tr,df),(sxy,tin)}/px
                                                         //  -> D23+: scrA(4608)+scrB@5184(4608)
    __shared__ __align__(16) uint2   s_PPv[TILE*FS];     // 9216 B vpassPP output
    __shared__ __align__(16) __half2 s_P2 [FROWS*FS];    // 5184 B (sf,cv) -> x^2v f32 (4608)
    // total 37248 B -> 4 blocks/CU

    const int tx  = threadIdx.x;          // 0..31
    const int ty  = threadIdx.y;          // 0..15
    const int tid = ty * 32 + tx;         // 0..511
    const int ryh = tid >> 4;             // 0..31  hpass row
    const int mch = tid & 15;             // 0..15  hpass col-pair
    const int t0  = blockIdx.x * TILE;
    const int f0  = blockIdx.y * TILE;
    const int b   = blockIdx.z;

    // 1D gaussian = normalized middle row of the separable 5x5 kernel
    float r0 = gk_in[10], r1 = gk_in[11], r2 = gk_in[12], r3 = gk_in[13], r4 = gk_in[14];
    float winv = __builtin_amdgcn_rcpf(r0 + r1 + r2 + r3 + r4);
    const float w[5] = {r0*winv, r1*winv, r2*winv, r3*winv, r4*winv};
    const __half2 wh2[5] = {pack_h2(w[0],w[0]), pack_h2(w[1],w[1]), pack_h2(w[2],w[2]),
                            pack_h2(w[3],w[3]), pack_h2(w[4],w[4])};
    const __half2 h2z    = pack_h2(0.f, 0.f);
    const __half2 two    = pack_h2(2.f, 2.f);
    const __half2 eighth = pack_h2(0.125f, 0.125f);

    // combined vertical pass over interleaved PP: PP -> PPv (uint4 ops)
    auto vpassPP = [&]() {
        const uint4* s = (const uint4*)s_PP;
        uint4* d = (uint4*)s_PPv;
        for (int idx = tid; idx < 16 * PPW4; idx += NTHR) {   // 288 items
            int rg = idx / PPW4, p = idx - rg * PPW4;
            int base = 2 * rg * PPW4 + p;
            uint4 vv[6];
            #pragma unroll
            for (int i = 0; i < 6; ++i) vv[i] = s[base + i * PPW4];
            __half2 a0=h2z,a1=h2z,a2=h2z,a3=h2z, b0=h2z,b1=h2z,b2=h2z,b3=h2z;
            #pragma unroll
            for (int i = 0; i < 5; ++i) {
                a0 = __hfma2(wh2[i], u2h(vv[i].x),   a0);
                a1 = __hfma2(wh2[i], u2h(vv[i].y),   a1);
                a2 = __hfma2(wh2[i], u2h(vv[i].z),   a2);
                a3 = __hfma2(wh2[i], u2h(vv[i].w),   a3);
                b0 = __hfma2(wh2[i], u2h(vv[i+1].x), b0);
                b1 = __hfma2(wh2[i], u2h(vv[i+1].y), b1);
                b2 = __hfma2(wh2[i], u2h(vv[i+1].z), b2);
                b3 = __hfma2(wh2[i], u2h(vv[i+1].w), b3);
            }
            uint4 oa, ob;
            oa.x=*(unsigned*)&a0; oa.y=*(unsigned*)&a1; oa.z=*(unsigned*)&a2; oa.w=*(unsigned*)&a3;
            ob.x=*(unsigned*)&b0; ob.y=*(unsigned*)&b1; ob.z=*(unsigned*)&b2; ob.w=*(unsigned*)&b3;
            d[base] = oa;
            d[base + PPW4] = ob;
        }
    };

    // uint4 row-pair vertical pass on an h2 field (FS=36 h2 = 9 uint4/row)
    auto vpass4 = [&](const __half2* src, __half2* dst) {
        const uint4* s = (const uint4*)src;
        uint4* d = (uint4*)dst;
        for (int idx = tid; idx < 16 * FH4; idx += NTHR) {   // 144 items
            int rg = idx / FH4, p = idx - rg * FH4;
            int base = 2 * rg * FH4 + p;
            uint4 vv[6];
            #pragma unroll
            for (int i = 0; i < 6; ++i) vv[i] = s[base + i * FH4];
            __half2 a0=h2z,a1=h2z,a2=h2z,a3=h2z, b0=h2z,b1=h2z,b2=h2z,b3=h2z;
            #pragma unroll
            for (int i = 0; i < 5; ++i) {
                a0 = __hfma2(wh2[i], u2h(vv[i].x),   a0);
                a1 = __hfma2(wh2[i], u2h(vv[i].y),   a1);
                a2 = __hfma2(wh2[i], u2h(vv[i].z),   a2);
                a3 = __hfma2(wh2[i], u2h(vv[i].w),   a3);
                b0 = __hfma2(wh2[i], u2h(vv[i+1].x), b0);
                b1 = __hfma2(wh2[i], u2h(vv[i+1].y), b1);
                b2 = __hfma2(wh2[i], u2h(vv[i+1].z), b2);
                b3 = __hfma2(wh2[i], u2h(vv[i+1].w), b3);
            }
            uint4 oa, ob;
            oa.x=*(unsigned*)&a0; oa.y=*(unsigned*)&a1; oa.z=*(unsigned*)&a2; oa.w=*(unsigned*)&a3;
            ob.x=*(unsigned*)&b0; ob.y=*(unsigned*)&b1; ob.z=*(unsigned*)&b2; ob.w=*(unsigned*)&b3;
            d[base] = oa;
            d[base + FH4] = ob;
        }
    };

    float acc[6][2];     // [plane][col 2mch / 2mch+1]
    #pragma unroll
    for (int k = 0; k < 6; ++k)
        #pragma unroll
        for (int s = 0; s < 2; ++s) acc[k][s] = 0.0f;

    const bool interior = (f0 >= 4) && (f0 + TILE + 4 <= F_DIM) &&
                          (t0 >= 4) && (t0 + TILE + 4 <= T_DIM);

    auto phaseABC = [&](const float* xp, auto FASTC) {
        constexpr bool FAST = decltype(FASTC)::value;

        // ---- Phase A: load x tile + halo 4 ----
        if (FAST) {
            // t0-4 is 16B-aligned (t0 % 32 == 0); rows 8192B -> float4 loads
            for (int idx = tid; idx < XROWS * 10; idx += NTHR) {
                int r  = idx / 10, c4 = idx - r * 10;
                float4 v = *(const float4*)(xp + (size_t)(f0 + r - 4) * T_DIM
                                               + (t0 + c4 * 4 - 4));
                *(float4*)&s_x[r * XS + c4 * 4] = v;
            }
        } else {
            for (int idx = tid; idx < XROWS * 20; idx += NTHR) {
                int r  = idx / 20, c2 = idx - r * 20;
                int gf = f0 + r - 4;
                int gt = t0 + c2 * 2 - 4;
                float2 v = make_float2(0.f, 0.f);
                if ((unsigned)gf < (unsigned)F_DIM && (unsigned)gt < (unsigned)T_DIM)
                    v = *(const float2*)(xp + (size_t)gf * T_DIM + gt);
                *(float2*)&s_x[r * XS + c2 * 2] = v;
            }
        }
        __syncthreads();

        // ---- Phase B: row-pair x col-pair items (19x19 = 361, single pass) ----
        if (tid < 19 * 19) {
            int g = tid / 19, m = tid - g * 19;   // g: row-pair, m: col-pair
            const float2* x2p = (const float2*)s_x;
            int base = (2 * g) * (XS/2) + m;
            float2 A0 = x2p[base],      B0 = x2p[base + 1];       // x row 2g
            float2 A1 = x2p[base + 20], B1 = x2p[base + 21];      // row 2g+1
            float2 A2 = x2p[base + 40], B2 = x2p[base + 41];      // row 2g+2
            float2 A3 = x2p[base + 60], B3 = x2p[base + 61];      // row 2g+3
            #pragma unroll
            for (int rr = 0; rr < 2; ++rr) {
                float2 a0 = rr ? A1 : A0, b0 = rr ? B1 : B0;
                float2 a1 = rr ? A2 : A1, b1 = rr ? B2 : B1;
                float2 a2 = rr ? A3 : A2, b2 = rr ? B3 : B2;
                int r = 2 * g + rr;
                // shared sobel column sums (identical formulas to r14)
                float c0 = a2.x - a0.x, c1 = a2.y - a0.y;
                float c2c = b2.x - b0.x, c3 = b2.y - b0.y;
                float s0 = fmaf(2.f, a1.x, a0.x + a2.x);
                float s1 = fmaf(2.f, a1.y, a0.y + a2.y);
                float s2 = fmaf(2.f, b1.x, b0.x + b2.x);
                float s3 = fmaf(2.f, b1.y, b0.y + b2.y);
                float gfvA = (fmaf(2.f, c1, c0) + c2c) * 0.125f;
                float gtvA = (s2 - s0) * 0.125f;
                float gfvB = (fmaf(2.f, c2c, c1) + c3) * 0.125f;
                float gtvB = (s3 - s1) * 0.125f;

                bool rin = (r >= 1) && (r < UROWS - 1);
                int  fiA = (r - 1) * FS + 2 * m - 1;
                int  gfr = f0 + r - 3;
                bool frOK = FAST || ((unsigned)gfr < (unsigned)F_DIM);

                #pragma unroll
                for (int jj = 0; jj < 2; ++jj) {
                    float gfv = jj ? gfvB : gfvA;
                    float gtv = jj ? gtvB : gtvA;
                    int   ccI = 2 * m + jj;
                    bool  okI = true;
                    if (!FAST) {
                        int gtc = t0 + ccI - 3;
                        okI = frOK & ((unsigned)gtc < (unsigned)T_DIM);
                    }
                    float ux = 0.f, uy = 0.f, trp = 0.f, dfp = 0.f, sxy = 0.f,
                          tin = 0.f, sf = 0.f;
                    if (okI) {
                        float gte = gtv + EPSF;
                        float g2f = gfv * gfv;
                        float d2  = fmaf(gte, gte, g2f);
                        float rh  = __builtin_amdgcn_rsqf(d2);
                        ux = gte * rh;
                        uy = gfv * rh;
                        float m2 = fmaf(gtv, gtv, g2f) + EPSF;
                        trp = m2;
                        dfp = m2 * (ux - uy) * (ux + uy);
                        sxy = m2 * ux * uy;
                        tin = __builtin_amdgcn_rcpf(1.0f + fabsf(gtv));
                        sf  = fabsf(gfv);
                    }
                    s_u[r * US + ccI + 1] = pack_h2(ux, uy);
                    bool pv = rin && (jj ? (m <= 17) : (m >= 1));
                    if (pv) {
                        int fi = fiA + jj;
                        __half2 h0 = pack_h2(trp, dfp);
                        __half2 h1 = pack_h2(sxy, tin);
                        uint2 pp;
                        pp.x = *(unsigned*)&h0; pp.y = *(unsigned*)&h1;
                        s_PP[fi] = pp;                       // single b64 write
                        s_P2[fi] = pack_h2(sf, 0.f);         // .y = cv from C
                    }
                }
            }
        }
        __syncthreads();

        // ---- Slot CD1: Phase C quad (u sobel -> P2.y) + vpassPP ----
        for (int q = tid; q < FROWS * FH4; q += NTHR) {   // 324 items
            int r = q / FH4, Q = q - r * FH4;
            const uint4* su4 = (const uint4*)s_u;
            int base = r * 10 + Q;                 // words 40r + 4Q
            uint4 ta4 = su4[base],      tb4 = su4[base + 1];
            uint4 ma4 = su4[base + 10], mb4 = su4[base + 11];
            uint4 ba4 = su4[base + 20], bb4 = su4[base + 21];
            __half2 t_[8] = {u2h(ta4.x),u2h(ta4.y),u2h(ta4.z),u2h(ta4.w),
                             u2h(tb4.x),u2h(tb4.y),u2h(tb4.z),u2h(tb4.w)};
            __half2 m_[8] = {u2h(ma4.x),u2h(ma4.y),u2h(ma4.z),u2h(ma4.w),
                             u2h(mb4.x),u2h(mb4.y),u2h(mb4.z),u2h(mb4.w)};
            __half2 b_[8] = {u2h(ba4.x),u2h(ba4.y),u2h(ba4.z),u2h(ba4.w),
                             u2h(bb4.x),u2h(bb4.y),u2h(bb4.z),u2h(bb4.w)};
            __half2 l_[7];
            #pragma unroll
            for (int k = 1; k <= 6; ++k) {
                __half2 s = __hadd2(t_[k], b_[k]);
                l_[k] = __hfma2(two, m_[k], s);
            }
            int gfr = f0 + r - 2;
            bool frOK = FAST || ((unsigned)gfr < (unsigned)F_DIM);
            #pragma unroll
            for (int jj = 0; jj < 4; ++jj) {
                __half2 tr = __hadd2(t_[jj+1], t_[jj+3]); tr = __hfma2(two, t_[jj+2], tr);
                __half2 br = __hadd2(b_[jj+1], b_[jj+3]); br = __hfma2(two, b_[jj+2], br);
                __half2 dx = __hmul2(__hsub2(l_[jj+3], l_[jj+1]), eighth);
                __half2 dy = __hmul2(__hsub2(br, tr), eighth);
                float2 fx = __half22float2(dx);
                float2 fy = __half22float2(dy);
                float cv = __builtin_amdgcn_sqrtf(
                    fmaf(fx.x, fx.x, fmaf(fx.y, fx.y,
                    fmaf(fy.x, fy.x, fy.y * fy.y))) + EPSF);
                int cc = 4 * Q + jj;
                if (!FAST) {
                    int gtc = t0 + cc - 2;
                    if (!(frOK & ((unsigned)gtc < (unsigned)T_DIM))) cv = 0.f;
                }
                ((__half*)s_P2)[2 * (r * FS + cc) + 1] = __float2half_rn(cv);
            }
        }
        vpassPP();                       // j0+j1 vertical in one pass
        __syncthreads();
    };

    for (int c = 0; c < C_DIM; ++c) {
        if (c) __syncthreads();

        const float* xp = x_in + (size_t)(b * C_DIM + c) * F_DIM * T_DIM;
        if (interior) phaseABC(xp, BoolC<true>{});
        else          phaseABC(xp, BoolC<false>{});

        // scratch areas inside dead s_PP after CD1:
        __half2* scrA  = (__half2*)s_PP;                         // 32x36 h2 (4608 B)
        uint2*   scrB  = (uint2*)((char*)s_PP + 5184);           // 32x18 uint2 (4608 B)

        // ====== Slot D23: j0h+j1h from PPv (3x b128) + entropy ;
        //        vpass4(P2->scrA) ; j3 vertical (u->scrB) ======
        {
            const uint4* v4 = (const uint4*)s_PPv;   // row = 18 uint4
            uint4 qa = v4[ryh * PPW4 + mch], qb = v4[ryh * PPW4 + mch + 1],
                  qc = v4[ryh * PPW4 + mch + 2];
            // px 2mch+p: trdf = {qa.x,qa.z,qb.x,qb.z,qc.x,qc.z}
            //            st   = {qa.y,qa.w,qb.y,qb.w,qc.y,qc.w}
            float2 e0 = __half22float2(u2h(qa.x)), e1 = __half22float2(u2h(qa.z));
            float2 e2 = __half22float2(u2h(qb.x)), e3 = __half22float2(u2h(qb.z));
            float2 e4 = __half22float2(u2h(qc.x)), e5 = __half22float2(u2h(qc.z));
            float trc[2], dfc[2];
            trc[0] = w[0]*e0.x + w[1]*e1.x + w[2]*e2.x + w[3]*e3.x + w[4]*e4.x;
            dfc[0] = w[0]*e0.y + w[1]*e1.y + w[2]*e2.y + w[3]*e3.y + w[4]*e4.y;
            trc[1] = w[0]*e1.x + w[1]*e2.x + w[2]*e3.x + w[3]*e4.x + w[4]*e5.x;
            dfc[1] = w[0]*e1.y + w[1]*e2.y + w[2]*e3.y + w[3]*e4.y + w[4]*e5.y;

            __half2 st0 = u2h(qa.y), st1 = u2h(qa.w), st2 = u2h(qb.y),
                    st3 = u2h(qb.w), st4 = u2h(qc.y), st5 = u2h(qc.w);
            __half2 aA = h2z, aB = h2z;
            aA = __hfma2(wh2[0], st0, aA);
            aA = __hfma2(wh2[1], st1, aA);
            aA = __hfma2(wh2[2], st2, aA);
            aA = __hfma2(wh2[3], st3, aA);
            aA = __hfma2(wh2[4], st4, aA);
            aB = __hfma2(wh2[0], st1, aB);
            aB = __hfma2(wh2[1], st2, aB);
            aB = __hfma2(wh2[2], st3, aB);
            aB = __hfma2(wh2[3], st4, aB);
            aB = __hfma2(wh2[4], st5, aB);
            float2 vc[2] = {__half22float2(aA), __half22float2(aB)};
            #pragma unroll
            for (int col = 0; col < 2; ++col) {
                float trace = trc[col], diff = dfc[col];
                float2 v = vc[col];
                float disc  = __builtin_amdgcn_sqrtf(
                                  fmaxf(diff * diff + 4.f * v.x * v.x, 0.f) + EPSF);
                float l1 = fmaxf(0.5f * (trace + disc), EPSF);
                float l2 = fmaxf(0.5f * (trace - disc), EPSF);
                float inv = __builtin_amdgcn_rcpf(l1 + l2 + EPSF);
                float p1 = l1 * inv, p2 = l2 * inv;
                // v_log_f32 IS log2 — matches reference's ln(p)/ln(2)
                float ent = -(p1 * __builtin_amdgcn_logf(p1 + EPSF)
                            + p2 * __builtin_amdgcn_logf(p2 + EPSF));
                acc[0][col] += 0.5f * clamp01(ent);
                acc[4][col] += 0.5f * clamp01(v.y);
            }

            vpass4(s_P2, scrA);          // j2 vertical: (sf,cv) -> scrA
            {
                // j3 vertical: u -> scrB, row-pair uint2 (odd word offset)
                const uint2* su2 = (const uint2*)s_u;
                for (int idx = tid; idx < 16 * FH2; idx += NTHR) {
                    int rg = idx / FH2, p = idx - rg * FH2;
                    const uint2* sp = su2 + (2 * rg + 1) * (US/2) + 1 + p;
                    uint2 vv[6];
                    #pragma unroll
                    for (int i = 0; i < 6; ++i) vv[i] = sp[i * (US/2)];
                    __half2 a0 = h2z, a1 = h2z, b0 = h2z, b1 = h2z;
                    #pragma unroll
                    for (int i = 0; i < 5; ++i) {
                        a0 = __hfma2(wh2[i], u2h(vv[i].x),     a0);
                        a1 = __hfma2(wh2[i], u2h(vv[i].y),     a1);
                        b0 = __hfma2(wh2[i], u2h(vv[i + 1].x), b0);
                        b1 = __hfma2(wh2[i], u2h(vv[i + 1].y), b1);
                    }
                    uint2 oa; oa.x = *(const unsigned*)&a0; oa.y = *(const unsigned*)&a1;
                    uint2 ob; ob.x = *(const unsigned*)&b0; ob.y = *(const unsigned*)&b1;
                    scrB[2 * rg * FH2 + p] = oa;
                    scrB[(2 * rg + 1) * FH2 + p] = ob;
                }
            }
        }
        __syncthreads();

        // ====== Slot D45: j2h (scrA) + j3h (scrB) col-pair ; v(x^2 -> s_P2 f32) ======
        {
            const uint2* p0q = (const uint2*)scrA;
            uint2 qa = p0q[ryh * FH2 + mch], qb = p0q[ryh * FH2 + mch + 1],
                  qc = p0q[ryh * FH2 + mch + 2];
            __half2 sA = h2z, sB = h2z;
            sA = __hfma2(wh2[0], u2h(qa.x), sA);
            sA = __hfma2(wh2[1], u2h(qa.y), sA);
            sA = __hfma2(wh2[2], u2h(qb.x), sA);
            sA = __hfma2(wh2[3], u2h(qb.y), sA);
            sA = __hfma2(wh2[4], u2h(qc.x), sA);
            sB = __hfma2(wh2[0], u2h(qa.y), sB);
            sB = __hfma2(wh2[1], u2h(qb.x), sB);
            sB = __hfma2(wh2[2], u2h(qb.y), sB);
            sB = __hfma2(wh2[3], u2h(qc.x), sB);
            sB = __hfma2(wh2[4], u2h(qc.y), sB);
            float2 s0 = __half22float2(sA), s1 = __half22float2(sB);   // (sp, cvs)
            acc[5][0] += 0.5f * clamp01(s0.x);  acc[2][0] += 0.5f * s0.y;
            acc[5][1] += 0.5f * clamp01(s1.x);  acc[2][1] += 0.5f * s1.y;

            const uint2* p1q = (const uint2*)scrB;
            uint2 ra = p1q[ryh * FH2 + mch], rb = p1q[ryh * FH2 + mch + 1],
                  rc = p1q[ryh * FH2 + mch + 2];
            __half2 uA = h2z, uB = h2z;
            uA = __hfma2(wh2[0], u2h(ra.x), uA);
            uA = __hfma2(wh2[1], u2h(ra.y), uA);
            uA = __hfma2(wh2[2], u2h(rb.x), uA);
            uA = __hfma2(wh2[3], u2h(rb.y), uA);
            uA = __hfma2(wh2[4], u2h(rc.x), uA);
            uB = __hfma2(wh2[0], u2h(ra.y), uB);
            uB = __hfma2(wh2[1], u2h(rb.x), uB);
            uB = __hfma2(wh2[2], u2h(rb.y), uB);
            uB = __hfma2(wh2[3], u2h(rc.x), uB);
            uB = __hfma2(wh2[4], u2h(rc.y), uB);
            float2 u0 = __half22float2(uA), u1 = __half22float2(uB);   // (ua, va)
            acc[1][0] += 0.5f * clamp01(
                __builtin_amdgcn_sqrtf(u0.x * u0.x + u0.y * u0.y + EPSF));
            acc[1][1] += 0.5f * clamp01(
                __builtin_amdgcn_sqrtf(u1.x * u1.x + u1.y * u1.y + EPSF));

            // j4 vertical: x^2 -> s_P2 (f32), row-pair float2
            const float2* sx2 = (const float2*)s_x;
            float2* dt2 = (float2*)s_P2;
            for (int idx = tid; idx < 16 * FH2; idx += NTHR) {
                int rg = idx / FH2, p = idx - rg * FH2;
                const float2* sp = sx2 + (2 * rg + 2) * (XS/2) + 1 + p;
                float2 sq[6];
                #pragma unroll
                for (int i = 0; i < 6; ++i) {
                    float2 v = sp[i * (XS/2)];
                    sq[i] = make_float2(v.x * v.x, v.y * v.y);
                }
                float aA = 0.f, bA = 0.f, aB = 0.f, bB = 0.f;
                #pragma unroll
                for (int i = 0; i < 5; ++i) {
                    aA = fmaf(w[i], sq[i].x,     aA);
                    bA = fmaf(w[i], sq[i].y,     bA);
                    aB = fmaf(w[i], sq[i + 1].x, aB);
                    bB = fmaf(w[i], sq[i + 1].y, bB);
                }
                dt2[2 * rg * FH2 + p] = make_float2(aA, bA);
                dt2[(2 * rg + 1) * FH2 + p] = make_float2(aB, bB);
            }
        }
        __syncthreads();

        // ====== Slot D6: j4h (le) col-pair + harmonic epilogue ======
        {
            const float2* tf = (const float2*)s_P2;   // element p = x^2v cols 2p,2p+1
            float2 q0 = tf[ryh * FH2 + mch], q1 = tf[ryh * FH2 + mch + 1],
                   q2 = tf[ryh * FH2 + mch + 2];
            float le0 = w[0]*q0.x + w[1]*q0.y + w[2]*q1.x + w[3]*q1.y + w[4]*q2.x;
            float le1 = w[0]*q0.y + w[1]*q1.x + w[2]*q1.y + w[3]*q2.x + w[4]*q2.y;
            const float2* sxf = (const float2*)s_x;
            float2 xm  = sxf[(ryh + 1) * (XS/2) + mch + 2];
            float2 x0v = sxf[(ryh + 4) * (XS/2) + mch + 2];
            float2 xpv = sxf[(ryh + 7) * (XS/2) + mch + 2];
            float hA = fabsf(2.f * x0v.x - xm.x - xpv.x);
            float hB = fabsf(2.f * x0v.y - xm.y - xpv.y);
            acc[3][0] += 0.5f * clamp01(hA * __builtin_amdgcn_rcpf(le0 + EPSF));
            acc[3][1] += 0.5f * clamp01(hB * __builtin_amdgcn_rcpf(le1 + EPSF));
        }
    }

    // ---- write 6 output planes: one float2 per plane per thread, coalesced ----
    const size_t plane = (size_t)B_DIM * F_DIM * T_DIM;
    const size_t base  = (size_t)b * F_DIM * T_DIM
                       + (size_t)(f0 + ryh) * T_DIM + t0 + 2 * mch;
    #pragma unroll
    for (int k = 0; k < 6; ++k)
        *(float2*)(out + k * plane + base) = make_float2(acc[k][0], acc[k][1]);
}

extern "C" void kernel_launch(void* const* d_in, const int* in_sizes, int n_in,
                              void* d_out, int out_size, void* d_ws, size_t ws_size,
                              hipStream_t stream) {
    const float* x  = (const float*)d_in[0];
    const float* gk = (const float*)d_in[1];
    float* out = (float*)d_out;
    dim3 grid(T_DIM / TILE, F_DIM / TILE, B_DIM);   // 64 x 8 x 8 = 4096 blocks
    dim3 block(32, 16);                             // 512 threads = 8 waves
    audio_struct_fused<<<grid, block, 0, stream>>>(x, gk, out);
}